// Round 9
// baseline (269.738 us; speedup 1.0000x reference)
//
#include <hip/hip_runtime.h>

typedef __attribute__((ext_vector_type(4))) float  f32x4;
typedef __attribute__((ext_vector_type(4))) float  float4v;
typedef __attribute__((ext_vector_type(4))) short  short4v;
typedef __attribute__((ext_vector_type(8))) short  short8v;
typedef __attribute__((ext_vector_type(8))) __bf16 bf16x8;

union Frag { short4v h[2]; short8v s8; };

__device__ __forceinline__ short f2bf(float f) {
  unsigned u = __builtin_bit_cast(unsigned, f);
  u = (u + 0x7fffu + ((u >> 16) & 1u)) >> 16;
  return (short)u;
}

__device__ __forceinline__ f32x4 mfma_bf16(const Frag& a, const Frag& b, f32x4 c) {
  return __builtin_amdgcn_mfma_f32_16x16x32_bf16(
      __builtin_bit_cast(bf16x8, a.s8), __builtin_bit_cast(bf16x8, b.s8), c, 0, 0, 0);
}

__device__ __forceinline__ int poscode(int i) {   // 11*(i/72) + (i/12)%6 + i%12
  int z = (i >= 72) ? 1 : 0;
  int rem = i - 72 * z;
  int y = rem / 12;
  return 11 * z + y + (rem - 12 * y);
}

// k-permute within a 32-chunk so one short8 at [lg*8] = MFMA operand order
__device__ __forceinline__ int kperm(int r) {
  return (r & 16) ? (((r - 16) >> 2) * 8 + 4 + (r & 3)) : ((r >> 2) * 8 + (r & 3));
}

// ---------------------------------------------------------------- K0: weights
__global__ __launch_bounds__(256) void k_transpose_w(
    const float* __restrict__ w_qkv, const float* __restrict__ w_o,
    short* __restrict__ wtq, short* __restrict__ wto) {
  int idx = blockIdx.x * 256 + threadIdx.x;
  if (idx < 110592) {
    int k = idx / 576, c = idx % 576;
    int kp = (k & ~31) + kperm(k & 31);
    wtq[c * 192 + kp] = f2bf(w_qkv[idx]);
  } else {
    int j = idx - 110592;
    int k = j / 192, c = j % 192;
    wto[c * 192 + k] = f2bf(w_o[j]);
  }
}

// ---------------------------------------------------------------- K0b: bias matrix
__global__ __launch_bounds__(256) void k_bias(
    const float* __restrict__ btab, float* __restrict__ bias6) {
  int idx = blockIdx.x * 256 + threadIdx.x;
  if (idx >= 124416) return;
  int h = idx / 20736, r = idx % 20736, m = r / 144, n = r % 144;
  bias6[idx] = btab[(poscode(m) - poscode(n) + 27) * 6 + h];
}

// ---------------------------------------------------------------- K1: QKV GEMM
// Swapped mfma(bw, a) -> output fragment is channel-contiguous per lane:
// epilogue = 36 short4 stores (was 144 scalar shorts).
__global__ __launch_bounds__(256, 2) void k_qkv(
    const float* __restrict__ x, const float* __restrict__ bqkv,
    const short* __restrict__ wtq, short* __restrict__ qkv) {
  __shared__ short a_lds[64][200];   // k-permuted per 32-chunk
  __shared__ short bT[576][40];      // k-permuted 32-chunk
  const int tid = threadIdx.x;
  const int lane = tid & 63, wv = tid >> 6;
  const int l15 = lane & 15, lg = lane >> 4;
  const int row0 = blockIdx.x * 64;

#pragma unroll
  for (int i = 0; i < 12; ++i) {
    int flat = tid + 256 * i;               // 64 rows x 48 float4 chunks
    int r = flat / 48, c4 = flat % 48;
    float4v xv = *(const float4v*)&x[(size_t)(row0 + r) * 192 + c4 * 4];
    short4v sv = { f2bf(xv[0]), f2bf(xv[1]), f2bf(xv[2]), f2bf(xv[3]) };
    int k = c4 * 4, rr = k & 31;
    int pos = (k & ~31) + ((rr & 16) ? (((rr - 16) >> 2) * 8 + 4) : ((rr >> 2) * 8));
    *(short4v*)&a_lds[r][pos] = sv;
  }

  f32x4 acc[36];
#pragma unroll
  for (int i = 0; i < 36; ++i) acc[i] = f32x4{0.f, 0.f, 0.f, 0.f};

  for (int kc = 0; kc < 6; ++kc) {
    __syncthreads();
#pragma unroll
    for (int i = 0; i < 9; ++i) {           // 576 cols x 4 s8 units
      int flat = tid + 256 * i;
      int c = flat >> 2, j = flat & 3;
      *(short8v*)&bT[c][j * 8] = *(const short8v*)&wtq[c * 192 + kc * 32 + j * 8];
    }
    __syncthreads();
    Frag a;
    a.s8 = *(const short8v*)&a_lds[wv * 16 + l15][kc * 32 + lg * 8];
#pragma unroll
    for (int cf = 0; cf < 36; ++cf) {
      Frag bw;
      bw.s8 = *(const short8v*)&bT[cf * 16 + l15][lg * 8];
      acc[cf] = mfma_bf16(bw, a, acc[cf]);  // SWAPPED: D^T, lane = 4 channels x 1 token
    }
  }

  // epilogue: lane holds c = cf*16+lg*4+{0..3} for token g = row0+wv*16+l15
  const int g = row0 + wv * 16 + l15;
  const int b_ = g / 144, n = g - b_ * 144;
#pragma unroll
  for (int cf = 0; cf < 36; ++cf) {
    int c0 = cf * 16 + lg * 4;
    int part = c0 / 192, rem = c0 % 192;
    int h = rem >> 5, d0 = rem & 31;
    int q4 = d0 >> 2;
    int dd0 = (part == 2) ? d0 : ((q4 < 4) ? q4 * 8 : (q4 - 4) * 8 + 4);
    float4v bias4 = *(const float4v*)&bqkv[c0];
    float scale = (part == 0) ? 0.17677669529663687f : 1.0f;
    short4v sv = { f2bf((acc[cf][0] + bias4[0]) * scale),
                   f2bf((acc[cf][1] + bias4[1]) * scale),
                   f2bf((acc[cf][2] + bias4[2]) * scale),
                   f2bf((acc[cf][3] + bias4[3]) * scale) };
    *(short4v*)&qkv[(size_t)((part * 1024 + b_) * 6 + h) * 4608 + n * 32 + dd0] = sv;
  }
}

// ---------------------------------------------------------------- K2: attention
// Round-8 structure; PV swapped to mfma(vt, p) -> output d-contiguous:
// 2 float4 stores per unit (was 8 scalar).
__global__ __launch_bounds__(512, 2) void k_attn(
    const short* __restrict__ qkv, const float* __restrict__ mask,
    const float* __restrict__ bias6, float* __restrict__ out) {
  __shared__ short k_l[6][144][40];   // d-permuted rows
  __shared__ short vt[6][32][168];    // [d][n-permuted 160]
  const int tid = threadIdx.x;
  const int lane = tid & 63, wv = tid >> 6;
  const int l15 = lane & 15, lg = lane >> 4;

  const int bid = blockIdx.x;
  const int b = ((bid >> 4) << 3) + (bid & 7) + (((bid >> 3) & 1) << 9);
  const int wm = b & 511;

  const size_t kbase = (size_t)(1024 + b) * 6 * 4608;
#pragma unroll
  for (int i = 0; i < 7; ++i) {
    int flat = tid + 512 * i;
    if (flat < 3456) {
      int h = flat / 576, r = flat % 576;
      int n = r >> 2, j8 = (r & 3) * 8;
      *(short8v*)&k_l[h][n][j8] =
          *(const short8v*)&qkv[kbase + (size_t)h * 4608 + n * 32 + j8];
    }
  }
#pragma unroll
  for (int i = 0; i < 6; ++i) {
    int flat = tid + 512 * i;
    int h = flat / 512, r = flat & 511;
    int d = r >> 4, jj = r & 15;
    vt[h][d][128 + (jj >> 2) * 8 + 4 + (jj & 3)] = 0;
  }
  const size_t vbase = (size_t)(2048 + b) * 6 * 4608;
#pragma unroll
  for (int i = 0; i < 14; ++i) {
    int flat = tid + 512 * i;
    if (flat < 6912) {
      int h = flat / 1152, r = flat % 1152;
      int n = r >> 3, d4 = (r & 7) * 4;
      short4v vv = *(const short4v*)&qkv[vbase + (size_t)h * 4608 + n * 32 + d4];
      int np = (n & ~31) + kperm(n & 31);
      vt[h][d4 + 0][np] = vv[0];
      vt[h][d4 + 1][np] = vv[1];
      vt[h][d4 + 2][np] = vv[2];
      vt[h][d4 + 3][np] = vv[3];
    }
  }
  __syncthreads();

  const float* maskw = &mask[(size_t)wm * 20736];
  const size_t qb = (size_t)b * 6 * 4608;

  f32x4 mrow[9];
  int q = 0;
  for (int unit = 0; unit < 7; ++unit) {
    int t, h;
    if (unit < 6) { t = wv; h = unit; }
    else { if (wv >= 6) break; t = 8; h = wv; }
    if (unit == 0 || unit == 6) {
      q = t * 16 + l15;
#pragma unroll
      for (int cf = 0; cf < 9; ++cf)
        mrow[cf] = *(const float4v*)&maskw[q * 144 + cf * 16 + lg * 4];
    }

    Frag aq;
    aq.s8 = *(const short8v*)&qkv[qb + (size_t)h * 4608 + q * 32 + lg * 8];

    f32x4 s[9];
#pragma unroll
    for (int cf = 0; cf < 9; ++cf) {
      Frag bk;
      bk.s8 = *(const short8v*)&k_l[h][cf * 16 + l15][lg * 8];
      s[cf] = mfma_bf16(bk, aq, f32x4{0.f, 0.f, 0.f, 0.f});
    }
    const float* brow = &bias6[(size_t)(h * 144 + q) * 144];
#pragma unroll
    for (int cf = 0; cf < 9; ++cf) {
      float4v bv = *(const float4v*)&brow[cf * 16 + lg * 4];
      s[cf] += mrow[cf] + bv;
    }

    float mx = s[0][0];
#pragma unroll
    for (int cf = 0; cf < 9; ++cf)
#pragma unroll
      for (int reg = 0; reg < 4; ++reg) mx = fmaxf(mx, s[cf][reg]);
    mx = fmaxf(mx, __shfl_xor(mx, 16, 64));
    mx = fmaxf(mx, __shfl_xor(mx, 32, 64));
    float sum = 0.f;
#pragma unroll
    for (int cf = 0; cf < 9; ++cf)
#pragma unroll
      for (int reg = 0; reg < 4; ++reg) {
        float e = __expf(s[cf][reg] - mx);
        s[cf][reg] = e;
        sum += e;
      }
    sum += __shfl_xor(sum, 16, 64);
    sum += __shfl_xor(sum, 32, 64);
    const float rinv = 1.0f / sum;
#pragma unroll
    for (int cf = 0; cf < 9; ++cf)
#pragma unroll
      for (int reg = 0; reg < 4; ++reg) s[cf][reg] *= rinv;

    // PV swapped: mfma(A=vt-frag, B=p-frag) -> D[d-local][token]
    f32x4 o0 = {0.f, 0.f, 0.f, 0.f}, o1 = {0.f, 0.f, 0.f, 0.f};
#pragma unroll
    for (int kc = 0; kc < 5; ++kc) {
      Frag p, b0, b1;
      p.h[0] = short4v{ f2bf(s[2 * kc][0]), f2bf(s[2 * kc][1]),
                        f2bf(s[2 * kc][2]), f2bf(s[2 * kc][3]) };
      p.h[1] = (kc < 4)
          ? short4v{ f2bf(s[2 * kc + 1][0]), f2bf(s[2 * kc + 1][1]),
                     f2bf(s[2 * kc + 1][2]), f2bf(s[2 * kc + 1][3]) }
          : short4v{0, 0, 0, 0};
      b0.s8 = *(const short8v*)&vt[h][l15][kc * 32 + lg * 8];
      b1.s8 = *(const short8v*)&vt[h][16 + l15][kc * 32 + lg * 8];
      o0 = mfma_bf16(b0, p, o0);
      o1 = mfma_bf16(b1, p, o1);
    }
    // lane holds d = lg*4+{0..3} (o0) / 16+lg*4+{0..3} (o1) for token q
    const size_t base = (size_t)(b * 144 + q) * 192 + h * 32;
    *(float4v*)&out[base + lg * 4]      = o0;
    *(float4v*)&out[base + 16 + lg * 4] = o1;
  }
}

// ---------------------------------------------------------------- K3: out proj (in-place)
// Swapped mfma(bw, a) -> 12 float4 stores (was 48 scalar).
__global__ __launch_bounds__(256, 2) void k_oproj(
    float* __restrict__ io, const float* __restrict__ bo,
    const short* __restrict__ wto) {
  __shared__ short a_lds[64][200];
  __shared__ short bT[192][40];
  const int tid = threadIdx.x;
  const int lane = tid & 63, wv = tid >> 6;
  const int l15 = lane & 15, lg = lane >> 4;
  const int row0 = blockIdx.x * 64;

#pragma unroll
  for (int i = 0; i < 12; ++i) {
    int flat = tid + 256 * i;
    int r = flat / 48, c4 = flat % 48;
    float4v xv = *(const float4v*)&io[(size_t)(row0 + r) * 192 + c4 * 4];
    short4v sv = { f2bf(xv[0]), f2bf(xv[1]), f2bf(xv[2]), f2bf(xv[3]) };
    *(short4v*)&a_lds[r][c4 * 4] = sv;
  }

  f32x4 acc[12];
#pragma unroll
  for (int i = 0; i < 12; ++i) acc[i] = f32x4{0.f, 0.f, 0.f, 0.f};

  for (int kc = 0; kc < 6; ++kc) {
    __syncthreads();
#pragma unroll
    for (int i = 0; i < 6; ++i) {
      int flat = tid + 256 * i;             // 192 cols x 8 quads
      int c = flat >> 3, kk = (flat & 7) << 2;
      *(short4v*)&bT[c][kk] = *(const short4v*)&wto[c * 192 + kc * 32 + kk];
    }
    __syncthreads();
    Frag a;
    a.h[0] = *(const short4v*)&a_lds[wv * 16 + l15][kc * 32 + lg * 4];
    a.h[1] = *(const short4v*)&a_lds[wv * 16 + l15][kc * 32 + lg * 4 + 16];
#pragma unroll
    for (int cf = 0; cf < 12; ++cf) {
      Frag bw;
      bw.h[0] = *(const short4v*)&bT[cf * 16 + l15][lg * 4];
      bw.h[1] = *(const short4v*)&bT[cf * 16 + l15][lg * 4 + 16];
      acc[cf] = mfma_bf16(bw, a, acc[cf]);  // SWAPPED
    }
  }

  const int g = row0 + wv * 16 + l15;
#pragma unroll
  for (int cf = 0; cf < 12; ++cf) {
    int c0 = cf * 16 + lg * 4;
    float4v bias4 = *(const float4v*)&bo[c0];
    *(float4v*)&io[(size_t)g * 192 + c0] = acc[cf] + bias4;
  }
}

extern "C" void kernel_launch(void* const* d_in, const int* in_sizes, int n_in,
                              void* d_out, int out_size, void* d_ws, size_t ws_size,
                              hipStream_t stream) {
  const float* x    = (const float*)d_in[0];
  const float* mask = (const float*)d_in[1];
  const float* wqkv = (const float*)d_in[2];
  const float* bqkv = (const float*)d_in[3];
  const float* wo   = (const float*)d_in[4];
  const float* bo   = (const float*)d_in[5];
  const float* btab = (const float*)d_in[6];
  float* out = (float*)d_out;

  short* wtq   = (short*)d_ws;               //    110,592 shorts (k-permuted)
  short* wto   = wtq + 110592;               //     36,864 shorts
  short* qkv   = wto + 36864;                // 84,934,656 shorts (162 MB)
  float* bias6 = (float*)(qkv + 84934656);   //    124,416 floats (497 KB)

  k_transpose_w<<<576, 256, 0, stream>>>(wqkv, wo, wtq, wto);
  k_bias<<<486, 256, 0, stream>>>(btab, bias6);
  k_qkv<<<2304, 256, 0, stream>>>(x, bqkv, wtq, qkv);
  k_attn<<<1024, 512, 0, stream>>>(qkv, mask, bias6, out);
  k_oproj<<<2304, 256, 0, stream>>>(out, bo, wto);
}